// Round 10
// baseline (642.112 us; speedup 1.0000x reference)
//
#include <hip/hip_runtime.h>
#include <hip/hip_bf16.h>
#include <stdint.h>

typedef unsigned short u16;
typedef __attribute__((ext_vector_type(8))) short short8;
typedef __attribute__((ext_vector_type(4))) float float4v;
typedef __attribute__((ext_vector_type(4))) unsigned int uint4v;

#define B_    2
#define N_    2048
#define DIM_  1024
#define H_    16
#define DH_   64
#define DI_   1024
#define EPS_  1.1920928955078125e-07f
#define LOG2_THETA 13.287712379549449f
#define SCL_  0.18033688011112042f   // (1/sqrt(64)) * log2(e)

__device__ __forceinline__ float bf2f(u16 u) {
    union { unsigned int i; float f; } v; v.i = ((unsigned int)u) << 16; return v.f;
}
__device__ __forceinline__ u16 f2bf(float f) {
    union { float f; unsigned int i; } v; v.f = f;
    unsigned int r = v.i + 0x7fff + ((v.i >> 16) & 1);
    return (u16)(r >> 16);
}
__device__ __forceinline__ unsigned int pack2bf(float a, float b) {
    union { float f; unsigned int i; } ua, ub; ua.f = a; ub.f = b;
    return ((ua.i + 0x8000u) >> 16) | ((ub.i + 0x8000u) & 0xffff0000u);
}
// key permutation within a 32-key group (matches S^T reg layout -> B-operand)
__device__ __forceinline__ int perm32(int n) {
    return (n & ~31) + (((n >> 2) & 3) * 8) + (((n >> 4) & 1) * 4) + (n & 3);
}

// ---------------- RMSNorm over DIM for fp32 tokens -> bf16 Xn ----------------
__global__ __launch_bounds__(256) void k_rmsnorm_x(
    const float* __restrict__ tok, const float* __restrict__ w, u16* __restrict__ xn) {
    int row = blockIdx.x;
    int t = threadIdx.x;
    const float* tr = tok + (size_t)row * DIM_;
    float vals[4];
    float ss = 0.f;
#pragma unroll
    for (int i = 0; i < 4; ++i) {
        float v = tr[t + i * 256];
        vals[i] = v; ss += v * v;
    }
#pragma unroll
    for (int o = 32; o; o >>= 1) ss += __shfl_xor(ss, o, 64);
    __shared__ float red[4];
    if ((t & 63) == 0) red[t >> 6] = ss;
    __syncthreads();
    ss = red[0] + red[1] + red[2] + red[3];
    float rs = rsqrtf(ss * (1.0f / DIM_) + EPS_);
    u16* orow = xn + (size_t)row * DIM_;
#pragma unroll
    for (int i = 0; i < 4; ++i) {
        int c = t + i * 256;
        orow[c] = f2bf(vals[i] * rs * w[c]);
    }
}

// ---------------- single weight transpose (K x N fp32) -> (N x K bf16) ----------------
__global__ __launch_bounds__(256) void k_transpose(
    const float* __restrict__ src, u16* __restrict__ dst, int K, int N) {
    __shared__ float tile[32][33];
    int n0 = blockIdx.x * 32, k0 = blockIdx.y * 32;
    int tx = threadIdx.x, ty = threadIdx.y;  // 32 x 8
#pragma unroll
    for (int i = 0; i < 4; ++i)
        tile[ty + 8 * i][tx] = src[(size_t)(k0 + ty + 8 * i) * N + n0 + tx];
    __syncthreads();
#pragma unroll
    for (int i = 0; i < 4; ++i)
        dst[(size_t)(n0 + ty + 8 * i) * K + k0 + tx] = f2bf(tile[tx][ty + 8 * i]);
}

// -------- merged q|k|v weight transpose -> WQKVT [7168][1024] bf16 --------
__global__ __launch_bounds__(256) void k_transpose_qkv(
    const float* __restrict__ w_q, const float* __restrict__ w_k,
    const float* __restrict__ w_v, u16* __restrict__ dst) {
    __shared__ float tile[32][33];
    int c0 = blockIdx.x * 32, k0 = blockIdx.y * 32;
    const float* src; int sN, sc0;
    if (c0 < 1024)      { src = w_q; sN = 1024; sc0 = c0; }
    else if (c0 < 4096) { src = w_k; sN = 3072; sc0 = c0 - 1024; }
    else                { src = w_v; sN = 3072; sc0 = c0 - 4096; }
    int tx = threadIdx.x, ty = threadIdx.y;  // 32 x 8
#pragma unroll
    for (int i = 0; i < 4; ++i)
        tile[ty + 8 * i][tx] = src[(size_t)(k0 + ty + 8 * i) * sN + sc0 + tx];
    __syncthreads();
#pragma unroll
    for (int i = 0; i < 4; ++i)
        dst[(size_t)(c0 + ty + 8 * i) * 1024 + k0 + tx] = f2bf(tile[tx][ty + 8 * i]);
}

// ------- V transpose: QKVB [B*N][7168] (V at col 4096+) -> Vt [(s*B+b)*H+h][64][N]
// with per-32-key permutation perm32 (matches S^T register layout) -------
__global__ __launch_bounds__(256) void k_transpose_v(
    const u16* __restrict__ QKVB, u16* __restrict__ Vt) {
    int y = blockIdx.y;                 // (s*B_+b)*H_+h
    int s = y >> 5;
    int b = (y >> 4) & 1;
    int h = y & 15;
    int n0 = blockIdx.x * 64;
    __shared__ u16 tile[64][72];
    int t = threadIdx.x;
#pragma unroll
    for (int i = 0; i < 2; ++i) {
        int idx = i * 256 + t;
        int row = idx >> 3, c = idx & 7;
        uint4v v = *(const uint4v*)(QKVB + ((size_t)(b * N_) + n0 + row) * 7168
                                        + 4096 + s * 1024 + h * 64 + c * 8);
        *(uint4v*)&tile[row][c * 8] = v;
    }
    __syncthreads();
    u16* out = Vt + (size_t)y * 64 * N_;
#pragma unroll
    for (int i = 0; i < 2; ++i) {
        int idx = i * 256 + t;
        int dh = idx >> 3, c = idx & 7;
#pragma unroll
        for (int j = 0; j < 8; ++j) {
            int n = c * 8 + j;
            out[(size_t)dh * N_ + n0 + perm32(n)] = tile[n][dh];
        }
    }
}

// ---------------- GEMM: C[MxN] = A[MxK] * Bt[NxK]^T  (m97 structure) ----------------
template <bool OUT_F32>
__global__ __launch_bounds__(256) void k_gemm_bt(
    const u16* __restrict__ A, const u16* __restrict__ Bt, void* __restrict__ Cv,
    int K, int Ncols) {
    __shared__ u16 As[128 * 32];
    __shared__ u16 Bs[128 * 32];
    int m0 = blockIdx.x * 128, n0 = blockIdx.y * 128;
    int t = threadIdx.x;
    int w = t >> 6, lane = t & 63, ln = lane & 15, quad = lane >> 4;
    int wm = w & 1, wn = w >> 1;
    float4v acc[4][4] = {};
    const u16* Ag = A + (size_t)m0 * K;
    const u16* Bg = Bt + (size_t)n0 * K;
    for (int k0 = 0; k0 < K; k0 += 32) {
        __syncthreads();
#pragma unroll
        for (int i = 0; i < 2; ++i) {
            int idx = i * 256 + t;
            int row = idx >> 2, kb = idx & 3;
            const u16* ga = Ag + (size_t)row * K + k0 + kb * 8;
            const u16* gb = Bg + (size_t)row * K + k0 + kb * 8;
            __builtin_amdgcn_global_load_lds(
                (const __attribute__((address_space(1))) void*)ga,
                (__attribute__((address_space(3))) void*)(As + idx * 8), 16, 0, 0);
            __builtin_amdgcn_global_load_lds(
                (const __attribute__((address_space(1))) void*)gb,
                (__attribute__((address_space(3))) void*)(Bs + idx * 8), 16, 0, 0);
        }
        asm volatile("s_waitcnt vmcnt(0)" ::: "memory");
        __syncthreads();
        short8 af[4], bfr[4];
#pragma unroll
        for (int mt = 0; mt < 4; ++mt)
            af[mt] = *(const short8*)(As + (wm * 64 + mt * 16 + ln) * 32 + quad * 8);
#pragma unroll
        for (int nt = 0; nt < 4; ++nt)
            bfr[nt] = *(const short8*)(Bs + (wn * 64 + nt * 16 + ln) * 32 + quad * 8);
#pragma unroll
        for (int mt = 0; mt < 4; ++mt)
#pragma unroll
            for (int nt = 0; nt < 4; ++nt)
                acc[mt][nt] = __builtin_amdgcn_mfma_f32_16x16x32_bf16(
                    af[mt], bfr[nt], acc[mt][nt], 0, 0, 0);
    }
#pragma unroll
    for (int mt = 0; mt < 4; ++mt)
#pragma unroll
        for (int nt = 0; nt < 4; ++nt)
#pragma unroll
            for (int r = 0; r < 4; ++r) {
                int row = m0 + wm * 64 + mt * 16 + quad * 4 + r;
                int col = n0 + wn * 64 + nt * 16 + ln;
                if (OUT_F32)
                    ((float*)Cv)[(size_t)row * Ncols + col] = acc[mt][nt][r];
                else
                    ((u16*)Cv)[(size_t)row * Ncols + col] = f2bf(acc[mt][nt][r]);
            }
}

// ---------------- RMSNorm(DH) + RoPE on K columns (bf16, fp32 w) ----------------
__global__ __launch_bounds__(256) void k_rms_rope_k(
    u16* __restrict__ buf, const float* __restrict__ w,
    int row_stride, int col0, int nsets) {
    int vid = blockIdx.x * 4 + (threadIdx.x >> 6);
    int lane = threadIdx.x & 63;
    int h = vid % H_;
    int s = (vid / H_) % nsets;
    int row = vid / (H_ * nsets);
    int n = row & (N_ - 1);
    u16* p = buf + (size_t)row * row_stride + col0 + s * 1024 + h * 64;
    float x = bf2f(p[lane]);
    float ss = x * x;
#pragma unroll
    for (int o = 32; o; o >>= 1) ss += __shfl_xor(ss, o, 64);
    float rs = rsqrtf(ss * (1.0f / 64.0f) + EPS_);
    float xn = x * rs * w[s * 64 + lane];
    float partner = __shfl_xor(xn, 1, 64);
    float inv = exp2f(-(float)(lane & ~1) * (LOG2_THETA / 64.0f));
    float fr = (float)n * inv;
    float sv, cv;
    __sincosf(fr, &sv, &cv);
    float out = xn * cv + ((lane & 1) ? partner : -partner) * sv;
    p[lane] = f2bf(out);
}

// ---------------- flash attention v10: transposed scores, no P LDS ----------------
// S^T via swapped MFMA operands (lane: key=quad*4+r, qrow=ln). exp outputs are
// directly the P^T B-operand (Vt keys permuted by perm32). O^T = V^T P^T.
// No P staging, no lgkm waits; LDS 32 KB -> 5 blocks/CU (LDS-bound).
__global__ __launch_bounds__(256, 4) void k_flash(
    const u16* __restrict__ Q, int q_stride,
    const u16* __restrict__ K, const u16* __restrict__ Vt,
    u16* __restrict__ O, u16* __restrict__ Ot,
    int kv_stride, int set_off, size_t o_set_stride) {
    int bh = blockIdx.x;                     // KV-stream on x: XCD L2 locality
    int qt = gridDim.y - 1 - blockIdx.y;     // long blocks first
    int s = blockIdx.z;
    int b = bh >> 4, h = bh & 15;
    int t = threadIdx.x;
    int w = t >> 6, lane = t & 63, ln = lane & 15, quad = lane >> 4;
    int lnx = ln & 7;
    int q0 = qt * 128;
    int qw = q0 + w * 32;

    const u16* Qb  = Q + ((size_t)b * N_) * q_stride + h * 64;
    const u16* Kb  = K + ((size_t)b * N_) * kv_stride + (size_t)s * set_off + h * 64;
    const u16* Vtb = Vt + (size_t)((s * B_ + b) * H_ + h) * (64 * (size_t)N_);

    __shared__ u16 Ks[2][64][64];            // chunk-XOR swizzled
    __shared__ u16 Vs[2][64][64];            // dh-major, perm32 keys, swizzled

    short8 ones;
#pragma unroll
    for (int j = 0; j < 8; ++j) ((u16*)&ones)[j] = 0x3F80;

    short8 qf[2][2];
    float mrow[2];                           // per-lane: bound for qrow = qg+ln
    float4v accO[2][4] = {};
    float4v accL[2] = {};
#pragma unroll
    for (int g = 0; g < 2; ++g) {
        int qg = qw + g * 16;
        int tokn = qg + ln;
        short8 raw[2];
#pragma unroll
        for (int f = 0; f < 2; ++f)
            raw[f] = *(const short8*)(Qb + (size_t)tokn * q_stride + f * 32 + quad * 8);
        float qn = 0.f;
#pragma unroll
        for (int f = 0; f < 2; ++f)
#pragma unroll
            for (int j = 0; j < 8; ++j) {
                float v = bf2f(((const u16*)&raw[f])[j]);
                qn += v * v;
            }
        qn += __shfl_xor(qn, 16, 64);
        qn += __shfl_xor(qn, 32, 64);        // lane now has ||q_{qg+ln}||^2
        mrow[g] = sqrtf(qn) * (8.0f * SCL_) * 1.03f + 1e-6f;
        // fused RoPE, folding SCL into Q
#pragma unroll
        for (int f = 0; f < 2; ++f) {
            u16 out8[8];
            int dbase = f * 32 + quad * 8;
#pragma unroll
            for (int tp = 0; tp < 4; ++tp) {
                int d = dbase + 2 * tp;
                float inv = exp2f((float)d * (-LOG2_THETA / 64.0f));
                float fr = (float)tokn * inv;
                float sv, cv;
                __sincosf(fr, &sv, &cv);
                float x0 = bf2f(((const u16*)&raw[f])[2 * tp]);
                float x1 = bf2f(((const u16*)&raw[f])[2 * tp + 1]);
                out8[2 * tp]     = f2bf((x0 * cv - x1 * sv) * SCL_);
                out8[2 * tp + 1] = f2bf((x1 * cv + x0 * sv) * SCL_);
            }
            qf[g][f] = *(const short8*)out8;
        }
    }

    int ntb = 2 * qt + 2;                    // block-uniform tile count

    auto stage = [&](int kt0, int buf) {
        int k0 = kt0 * 64;
#pragma unroll
        for (int i = 0; i < 2; ++i) {
            int idx = i * 256 + t;
            int row = idx >> 3, c = idx & 7;
            int csrc = ((c ^ (row & 7)) * 8);
            const u16* ga = Kb + (size_t)(k0 + row) * kv_stride + csrc;
            __builtin_amdgcn_global_load_lds(
                (const __attribute__((address_space(1))) void*)ga,
                (__attribute__((address_space(3))) void*)&Ks[buf][row][c * 8], 16, 0, 0);
            const u16* gv = Vtb + (size_t)row * N_ + k0 + csrc;
            __builtin_amdgcn_global_load_lds(
                (const __attribute__((address_space(1))) void*)gv,
                (__attribute__((address_space(3))) void*)&Vs[buf][row][c * 8], 16, 0, 0);
        }
    };
    stage(0, 0);

    for (int kt0 = 0; kt0 < ntb; ++kt0) {
        asm volatile("s_waitcnt vmcnt(0)" ::: "memory");
        __syncthreads();
        if (kt0 + 1 < ntb) stage(kt0 + 1, (kt0 + 1) & 1);
        int buf = kt0 & 1;
        int k0 = kt0 * 64;
        if (k0 > qw + 31) continue;          // wave-causal skip (one barrier/iter preserved)

        short8 kf[4][2];
#pragma unroll
        for (int kt = 0; kt < 4; ++kt) {
            const u16* krow = &Ks[buf][kt * 16 + ln][0];
            kf[kt][0] = *(const short8*)(krow + ((quad ^ lnx) * 8));
            kf[kt][1] = *(const short8*)(krow + (((4 + quad) ^ lnx) * 8));
        }

        short8 pb[2][2];                     // P^T B-fragments [g][32-key chunk]
#pragma unroll
        for (int g = 0; g < 2; ++g) {
            int qg = qw + g * 16;
            // S^T: D[key=quad*4+r][qrow=ln], C-init = -m(qrow)
            float4v st[4];
#pragma unroll
            for (int kt = 0; kt < 4; ++kt) {
                float4v sa = {-mrow[g], -mrow[g], -mrow[g], -mrow[g]};
                sa = __builtin_amdgcn_mfma_f32_16x16x32_bf16(kf[kt][0], qf[g][0], sa, 0, 0, 0);
                sa = __builtin_amdgcn_mfma_f32_16x16x32_bf16(kf[kt][1], qf[g][1], sa, 0, 0, 0);
                st[kt] = sa;
            }
            if (k0 + 63 <= qg) {
                // fully unmasked (wave-uniform fast path)
#pragma unroll
                for (int c = 0; c < 2; ++c) {
                    uint4v pk;
#pragma unroll
                    for (int kt2 = 0; kt2 < 2; ++kt2) {
                        float e0 = exp2f(st[c * 2 + kt2][0]);
                        float e1 = exp2f(st[c * 2 + kt2][1]);
                        float e2 = exp2f(st[c * 2 + kt2][2]);
                        float e3 = exp2f(st[c * 2 + kt2][3]);
                        pk[kt2 * 2 + 0] = pack2bf(e0, e1);
                        pk[kt2 * 2 + 1] = pack2bf(e2, e3);
                    }
                    pb[g][c] = *(short8*)&pk;
                }
            } else {
                int qr = qg + ln;            // this lane's q-row
#pragma unroll
                for (int c = 0; c < 2; ++c) {
                    uint4v pk;
#pragma unroll
                    for (int kt2 = 0; kt2 < 2; ++kt2) {
                        int kt = c * 2 + kt2;
                        float e[4];
#pragma unroll
                        for (int r = 0; r < 4; ++r) {
                            int kg = k0 + kt * 16 + quad * 4 + r;
                            float arg = (kg <= qr) ? st[kt][r] : -1e30f;
                            e[r] = exp2f(arg);
                        }
                        pk[kt2 * 2 + 0] = pack2bf(e[0], e[1]);
                        pk[kt2 * 2 + 1] = pack2bf(e[2], e[3]);
                    }
                    pb[g][c] = *(short8*)&pk;
                }
            }
        }

        // O^T += V^T P^T ; l += ones P^T
#pragma unroll
        for (int dc = 0; dc < 4; ++dc) {
            const u16* vrow = &Vs[buf][dc * 16 + ln][0];
            short8 vf0 = *(const short8*)(vrow + ((quad ^ lnx) * 8));
            short8 vf1 = *(const short8*)(vrow + (((4 + quad) ^ lnx) * 8));
#pragma unroll
            for (int g = 0; g < 2; ++g) {
                accO[g][dc] = __builtin_amdgcn_mfma_f32_16x16x32_bf16(vf0, pb[g][0], accO[g][dc], 0, 0, 0);
                accO[g][dc] = __builtin_amdgcn_mfma_f32_16x16x32_bf16(vf1, pb[g][1], accO[g][dc], 0, 0, 0);
            }
        }
#pragma unroll
        for (int g = 0; g < 2; ++g) {
            accL[g] = __builtin_amdgcn_mfma_f32_16x16x32_bf16(ones, pb[g][0], accL[g], 0, 0, 0);
            accL[g] = __builtin_amdgcn_mfma_f32_16x16x32_bf16(ones, pb[g][1], accL[g], 0, 0, 0);
        }
    }

#pragma unroll
    for (int g = 0; g < 2; ++g) {
        float rinv = 1.0f / accL[g][0];      // l for qrow=ln (same in all rows)
        int qg = qw + g * 16;
        int qr = qg + ln;
        if (s == 2) {
            // O^T is already the transposed layout; apply perm32 on qrow for L2's Vt
            u16* Otb = Ot + (size_t)(b * H_ + h) * (64 * (size_t)N_);
            int pos = perm32(qr & (N_ - 1)) + (qr & ~(N_ - 1));
#pragma unroll
            for (int dc = 0; dc < 4; ++dc)
#pragma unroll
                for (int r = 0; r < 4; ++r)
                    Otb[(size_t)(dc * 16 + quad * 4 + r) * N_ + pos] =
                        f2bf(accO[g][dc][r] * rinv);
        } else {
            u16* Ob = O + (size_t)s * o_set_stride + ((size_t)b * N_) * DI_ + h * 64;
#pragma unroll
            for (int dc = 0; dc < 4; ++dc) {
                uint2 pk;
                pk.x = pack2bf(accO[g][dc][0] * rinv, accO[g][dc][1] * rinv);
                pk.y = pack2bf(accO[g][dc][2] * rinv, accO[g][dc][3] * rinv);
                *(uint2*)(Ob + (size_t)qr * DI_ + dc * 16 + quad * 4) = pk;
            }
        }
    }
}

extern "C" void kernel_launch(void* const* d_in, const int* in_sizes, int n_in,
                              void* d_out, int out_size, void* d_ws, size_t ws_size,
                              hipStream_t stream) {
    const float* tok     = (const float*)d_in[0];
    const float* w_norm  = (const float*)d_in[1];
    const float* w_q     = (const float*)d_in[2];
    const float* w_k     = (const float*)d_in[3];
    const float* w_v     = (const float*)d_in[4];
    const float* w_keyn  = (const float*)d_in[5];
    const float* w_nestk = (const float*)d_in[6];
    const float* w_o     = (const float*)d_in[7];

    char* ws = (char*)d_ws;
    const size_t MB = 1024 * 1024;
    u16* QKVB  = (u16*)(ws + 0 * MB);    // [0,56)   4096 x 7168 bf16
    u16* VtB   = (u16*)(ws + 56 * MB);   // [56,80)
    u16* NQKV  = (u16*)(ws + 80 * MB);   // [80,96)  sets 0,1 token-major (written by L1)
    u16* WQKVT = (u16*)(ws + 80 * MB);   // [80,94)  dead before L1 writes NQKV
    u16* NVt   = (u16*)(ws + 96 * MB);   // [96,104) set 2 transposed (written by L1)
    u16* XN    = (u16*)(ws + 96 * MB);   // [96,104) dead after QKV GEMM
    u16* OUT2  = (u16*)(ws + 104 * MB);  // [104,112) written by L2
    u16* WOT   = (u16*)(ws + 80 * MB);   // [80,82)  re-created after L2 (NQKV dead)

    const size_t SET = (size_t)B_ * N_ * DI_;

    k_transpose_qkv<<<dim3(224, 32), dim3(32, 8), 0, stream>>>(w_q, w_k, w_v, WQKVT);

    k_rmsnorm_x<<<B_ * N_, 256, 0, stream>>>(tok, w_norm, XN);

    k_gemm_bt<false><<<dim3(32, 56), 256, 0, stream>>>(XN, WQKVT, QKVB, 1024, 7168);

    k_transpose_v<<<dim3(N_ / 64, 3 * B_ * H_), 256, 0, stream>>>(QKVB, VtB);

    k_rms_rope_k<<<(B_ * N_ * 3 * H_) / 4, 256, 0, stream>>>(QKVB, w_keyn, 7168, 1024, 3);

    k_flash<<<dim3(B_ * H_, N_ / 128, 3), 256, 0, stream>>>(
        QKVB, 7168, QKVB + 1024, VtB, NQKV, NVt, 7168, 1024, SET);

    k_rms_rope_k<<<(B_ * N_ * H_) / 4, 256, 0, stream>>>(NQKV + SET, w_nestk, 1024, 0, 1);

    k_flash<<<dim3(B_ * H_, N_ / 128, 1), 256, 0, stream>>>(
        NQKV, 1024, NQKV + SET, NVt, OUT2, NVt /*unused*/, 1024, 0, 0);

    k_transpose<<<dim3(32, 32), dim3(32, 8), 0, stream>>>(w_o, WOT, 1024, 1024);
    k_gemm_bt<true><<<dim3(32, 8), 256, 0, stream>>>(OUT2, WOT, (float*)d_out, 1024, 1024);
}

// Round 11
// 442.396 us; speedup vs baseline: 1.4514x; 1.4514x over previous
//
#include <hip/hip_runtime.h>
#include <hip/hip_bf16.h>
#include <stdint.h>

typedef unsigned short u16;
typedef __attribute__((ext_vector_type(8))) short short8;
typedef __attribute__((ext_vector_type(4))) float float4v;
typedef __attribute__((ext_vector_type(4))) unsigned int uint4v;

#define B_    2
#define N_    2048
#define DIM_  1024
#define H_    16
#define DH_   64
#define DI_   1024
#define EPS_  1.1920928955078125e-07f
#define LOG2_THETA 13.287712379549449f
#define SCL_  0.18033688011112042f   // (1/sqrt(64)) * log2(e)

__device__ __forceinline__ float bf2f(u16 u) {
    union { unsigned int i; float f; } v; v.i = ((unsigned int)u) << 16; return v.f;
}
__device__ __forceinline__ u16 f2bf(float f) {
    union { float f; unsigned int i; } v; v.f = f;
    unsigned int r = v.i + 0x7fff + ((v.i >> 16) & 1);
    return (u16)(r >> 16);
}
__device__ __forceinline__ unsigned int pack2bf(float a, float b) {
    union { float f; unsigned int i; } ua, ub; ua.f = a; ub.f = b;
    return ((ua.i + 0x8000u) >> 16) | ((ub.i + 0x8000u) & 0xffff0000u);
}
// key permutation within a 32-key group (matches S^T reg layout -> B-operand)
__device__ __forceinline__ int perm32(int n) {
    return (n & ~31) + (((n >> 2) & 3) * 8) + (((n >> 4) & 1) * 4) + (n & 3);
}

// ---------------- RMSNorm over DIM for fp32 tokens -> bf16 Xn ----------------
__global__ __launch_bounds__(256) void k_rmsnorm_x(
    const float* __restrict__ tok, const float* __restrict__ w, u16* __restrict__ xn) {
    int row = blockIdx.x;
    int t = threadIdx.x;
    const float* tr = tok + (size_t)row * DIM_;
    float vals[4];
    float ss = 0.f;
#pragma unroll
    for (int i = 0; i < 4; ++i) {
        float v = tr[t + i * 256];
        vals[i] = v; ss += v * v;
    }
#pragma unroll
    for (int o = 32; o; o >>= 1) ss += __shfl_xor(ss, o, 64);
    __shared__ float red[4];
    if ((t & 63) == 0) red[t >> 6] = ss;
    __syncthreads();
    ss = red[0] + red[1] + red[2] + red[3];
    float rs = rsqrtf(ss * (1.0f / DIM_) + EPS_);
    u16* orow = xn + (size_t)row * DIM_;
#pragma unroll
    for (int i = 0; i < 4; ++i) {
        int c = t + i * 256;
        orow[c] = f2bf(vals[i] * rs * w[c]);
    }
}

// ---------------- single weight transpose (K x N fp32) -> (N x K bf16) ----------------
__global__ __launch_bounds__(256) void k_transpose(
    const float* __restrict__ src, u16* __restrict__ dst, int K, int N) {
    __shared__ float tile[32][33];
    int n0 = blockIdx.x * 32, k0 = blockIdx.y * 32;
    int tx = threadIdx.x, ty = threadIdx.y;  // 32 x 8
#pragma unroll
    for (int i = 0; i < 4; ++i)
        tile[ty + 8 * i][tx] = src[(size_t)(k0 + ty + 8 * i) * N + n0 + tx];
    __syncthreads();
#pragma unroll
    for (int i = 0; i < 4; ++i)
        dst[(size_t)(n0 + ty + 8 * i) * K + k0 + tx] = f2bf(tile[tx][ty + 8 * i]);
}

// -------- merged q|k|v weight transpose -> WQKVT [7168][1024] bf16 --------
__global__ __launch_bounds__(256) void k_transpose_qkv(
    const float* __restrict__ w_q, const float* __restrict__ w_k,
    const float* __restrict__ w_v, u16* __restrict__ dst) {
    __shared__ float tile[32][33];
    int c0 = blockIdx.x * 32, k0 = blockIdx.y * 32;
    const float* src; int sN, sc0;
    if (c0 < 1024)      { src = w_q; sN = 1024; sc0 = c0; }
    else if (c0 < 4096) { src = w_k; sN = 3072; sc0 = c0 - 1024; }
    else                { src = w_v; sN = 3072; sc0 = c0 - 4096; }
    int tx = threadIdx.x, ty = threadIdx.y;  // 32 x 8
#pragma unroll
    for (int i = 0; i < 4; ++i)
        tile[ty + 8 * i][tx] = src[(size_t)(k0 + ty + 8 * i) * sN + sc0 + tx];
    __syncthreads();
#pragma unroll
    for (int i = 0; i < 4; ++i)
        dst[(size_t)(c0 + ty + 8 * i) * 1024 + k0 + tx] = f2bf(tile[tx][ty + 8 * i]);
}

// ------- V transpose: QKVB [B*N][7168] (V at col 4096+) -> Vt [(s*B+b)*H+h][64][N]
// with per-32-key permutation perm32 (matches S^T register layout) -------
__global__ __launch_bounds__(256) void k_transpose_v(
    const u16* __restrict__ QKVB, u16* __restrict__ Vt) {
    int y = blockIdx.y;                 // (s*B_+b)*H_+h
    int s = y >> 5;
    int b = (y >> 4) & 1;
    int h = y & 15;
    int n0 = blockIdx.x * 64;
    __shared__ u16 tile[64][72];
    int t = threadIdx.x;
#pragma unroll
    for (int i = 0; i < 2; ++i) {
        int idx = i * 256 + t;
        int row = idx >> 3, c = idx & 7;
        uint4v v = *(const uint4v*)(QKVB + ((size_t)(b * N_) + n0 + row) * 7168
                                        + 4096 + s * 1024 + h * 64 + c * 8);
        *(uint4v*)&tile[row][c * 8] = v;
    }
    __syncthreads();
    u16* out = Vt + (size_t)y * 64 * N_;
#pragma unroll
    for (int i = 0; i < 2; ++i) {
        int idx = i * 256 + t;
        int dh = idx >> 3, c = idx & 7;
#pragma unroll
        for (int j = 0; j < 8; ++j) {
            int n = c * 8 + j;
            out[(size_t)dh * N_ + n0 + perm32(n)] = tile[n][dh];
        }
    }
}

// ---------------- GEMM: C[MxN] = A[MxK] * Bt[NxK]^T  (m97 structure) ----------------
template <bool OUT_F32>
__global__ __launch_bounds__(256) void k_gemm_bt(
    const u16* __restrict__ A, const u16* __restrict__ Bt, void* __restrict__ Cv,
    int K, int Ncols) {
    __shared__ u16 As[128 * 32];
    __shared__ u16 Bs[128 * 32];
    int m0 = blockIdx.x * 128, n0 = blockIdx.y * 128;
    int t = threadIdx.x;
    int w = t >> 6, lane = t & 63, ln = lane & 15, quad = lane >> 4;
    int wm = w & 1, wn = w >> 1;
    float4v acc[4][4] = {};
    const u16* Ag = A + (size_t)m0 * K;
    const u16* Bg = Bt + (size_t)n0 * K;
    for (int k0 = 0; k0 < K; k0 += 32) {
        __syncthreads();
#pragma unroll
        for (int i = 0; i < 2; ++i) {
            int idx = i * 256 + t;
            int row = idx >> 2, kb = idx & 3;
            const u16* ga = Ag + (size_t)row * K + k0 + kb * 8;
            const u16* gb = Bg + (size_t)row * K + k0 + kb * 8;
            __builtin_amdgcn_global_load_lds(
                (const __attribute__((address_space(1))) void*)ga,
                (__attribute__((address_space(3))) void*)(As + idx * 8), 16, 0, 0);
            __builtin_amdgcn_global_load_lds(
                (const __attribute__((address_space(1))) void*)gb,
                (__attribute__((address_space(3))) void*)(Bs + idx * 8), 16, 0, 0);
        }
        asm volatile("s_waitcnt vmcnt(0)" ::: "memory");
        __syncthreads();
        short8 af[4], bfr[4];
#pragma unroll
        for (int mt = 0; mt < 4; ++mt)
            af[mt] = *(const short8*)(As + (wm * 64 + mt * 16 + ln) * 32 + quad * 8);
#pragma unroll
        for (int nt = 0; nt < 4; ++nt)
            bfr[nt] = *(const short8*)(Bs + (wn * 64 + nt * 16 + ln) * 32 + quad * 8);
#pragma unroll
        for (int mt = 0; mt < 4; ++mt)
#pragma unroll
            for (int nt = 0; nt < 4; ++nt)
                acc[mt][nt] = __builtin_amdgcn_mfma_f32_16x16x32_bf16(
                    af[mt], bfr[nt], acc[mt][nt], 0, 0, 0);
    }
#pragma unroll
    for (int mt = 0; mt < 4; ++mt)
#pragma unroll
        for (int nt = 0; nt < 4; ++nt)
#pragma unroll
            for (int r = 0; r < 4; ++r) {
                int row = m0 + wm * 64 + mt * 16 + quad * 4 + r;
                int col = n0 + wn * 64 + nt * 16 + ln;
                if (OUT_F32)
                    ((float*)Cv)[(size_t)row * Ncols + col] = acc[mt][nt][r];
                else
                    ((u16*)Cv)[(size_t)row * Ncols + col] = f2bf(acc[mt][nt][r]);
            }
}

// ---------------- RMSNorm(DH) + RoPE on K columns (bf16, fp32 w) ----------------
__global__ __launch_bounds__(256) void k_rms_rope_k(
    u16* __restrict__ buf, const float* __restrict__ w,
    int row_stride, int col0, int nsets) {
    int vid = blockIdx.x * 4 + (threadIdx.x >> 6);
    int lane = threadIdx.x & 63;
    int h = vid % H_;
    int s = (vid / H_) % nsets;
    int row = vid / (H_ * nsets);
    int n = row & (N_ - 1);
    u16* p = buf + (size_t)row * row_stride + col0 + s * 1024 + h * 64;
    float x = bf2f(p[lane]);
    float ss = x * x;
#pragma unroll
    for (int o = 32; o; o >>= 1) ss += __shfl_xor(ss, o, 64);
    float rs = rsqrtf(ss * (1.0f / 64.0f) + EPS_);
    float xn = x * rs * w[s * 64 + lane];
    float partner = __shfl_xor(xn, 1, 64);
    float inv = exp2f(-(float)(lane & ~1) * (LOG2_THETA / 64.0f));
    float fr = (float)n * inv;
    float sv, cv;
    __sincosf(fr, &sv, &cv);
    float out = xn * cv + ((lane & 1) ? partner : -partner) * sv;
    p[lane] = f2bf(out);
}

// ---------------- flash attention v11: S^T structure at non-spilling occupancy ----------------
// Identical to v10 except __launch_bounds__(256,3): w=4 capped arch-VGPRs at 64 and
// spilled the ~90-reg working set to scratch (R8/R10 FETCH/WRITE explosions).
__global__ __launch_bounds__(256, 3) void k_flash(
    const u16* __restrict__ Q, int q_stride,
    const u16* __restrict__ K, const u16* __restrict__ Vt,
    u16* __restrict__ O, u16* __restrict__ Ot,
    int kv_stride, int set_off, size_t o_set_stride) {
    int bh = blockIdx.x;                     // KV-stream on x: XCD L2 locality
    int qt = gridDim.y - 1 - blockIdx.y;     // long blocks first
    int s = blockIdx.z;
    int b = bh >> 4, h = bh & 15;
    int t = threadIdx.x;
    int w = t >> 6, lane = t & 63, ln = lane & 15, quad = lane >> 4;
    int lnx = ln & 7;
    int q0 = qt * 128;
    int qw = q0 + w * 32;

    const u16* Qb  = Q + ((size_t)b * N_) * q_stride + h * 64;
    const u16* Kb  = K + ((size_t)b * N_) * kv_stride + (size_t)s * set_off + h * 64;
    const u16* Vtb = Vt + (size_t)((s * B_ + b) * H_ + h) * (64 * (size_t)N_);

    __shared__ u16 Ks[2][64][64];            // chunk-XOR swizzled
    __shared__ u16 Vs[2][64][64];            // dh-major, perm32 keys, swizzled

    short8 ones;
#pragma unroll
    for (int j = 0; j < 8; ++j) ((u16*)&ones)[j] = 0x3F80;

    short8 qf[2][2];
    float mrow[2];                           // per-lane: bound for qrow = qg+ln
    float4v accO[2][4] = {};
    float4v accL[2] = {};
#pragma unroll
    for (int g = 0; g < 2; ++g) {
        int qg = qw + g * 16;
        int tokn = qg + ln;
        short8 raw[2];
#pragma unroll
        for (int f = 0; f < 2; ++f)
            raw[f] = *(const short8*)(Qb + (size_t)tokn * q_stride + f * 32 + quad * 8);
        float qn = 0.f;
#pragma unroll
        for (int f = 0; f < 2; ++f)
#pragma unroll
            for (int j = 0; j < 8; ++j) {
                float v = bf2f(((const u16*)&raw[f])[j]);
                qn += v * v;
            }
        qn += __shfl_xor(qn, 16, 64);
        qn += __shfl_xor(qn, 32, 64);        // lane now has ||q_{qg+ln}||^2
        mrow[g] = sqrtf(qn) * (8.0f * SCL_) * 1.03f + 1e-6f;
        // fused RoPE, folding SCL into Q
#pragma unroll
        for (int f = 0; f < 2; ++f) {
            u16 out8[8];
            int dbase = f * 32 + quad * 8;
#pragma unroll
            for (int tp = 0; tp < 4; ++tp) {
                int d = dbase + 2 * tp;
                float inv = exp2f((float)d * (-LOG2_THETA / 64.0f));
                float fr = (float)tokn * inv;
                float sv, cv;
                __sincosf(fr, &sv, &cv);
                float x0 = bf2f(((const u16*)&raw[f])[2 * tp]);
                float x1 = bf2f(((const u16*)&raw[f])[2 * tp + 1]);
                out8[2 * tp]     = f2bf((x0 * cv - x1 * sv) * SCL_);
                out8[2 * tp + 1] = f2bf((x1 * cv + x0 * sv) * SCL_);
            }
            qf[g][f] = *(const short8*)out8;
        }
    }

    int ntb = 2 * qt + 2;                    // block-uniform tile count

    auto stage = [&](int kt0, int buf) {
        int k0 = kt0 * 64;
#pragma unroll
        for (int i = 0; i < 2; ++i) {
            int idx = i * 256 + t;
            int row = idx >> 3, c = idx & 7;
            int csrc = ((c ^ (row & 7)) * 8);
            const u16* ga = Kb + (size_t)(k0 + row) * kv_stride + csrc;
            __builtin_amdgcn_global_load_lds(
                (const __attribute__((address_space(1))) void*)ga,
                (__attribute__((address_space(3))) void*)&Ks[buf][row][c * 8], 16, 0, 0);
            const u16* gv = Vtb + (size_t)row * N_ + k0 + csrc;
            __builtin_amdgcn_global_load_lds(
                (const __attribute__((address_space(1))) void*)gv,
                (__attribute__((address_space(3))) void*)&Vs[buf][row][c * 8], 16, 0, 0);
        }
    };
    stage(0, 0);

    for (int kt0 = 0; kt0 < ntb; ++kt0) {
        asm volatile("s_waitcnt vmcnt(0)" ::: "memory");
        __syncthreads();
        if (kt0 + 1 < ntb) stage(kt0 + 1, (kt0 + 1) & 1);
        int buf = kt0 & 1;
        int k0 = kt0 * 64;
        if (k0 > qw + 31) continue;          // wave-causal skip (one barrier/iter preserved)

        short8 kf[4][2];
#pragma unroll
        for (int kt = 0; kt < 4; ++kt) {
            const u16* krow = &Ks[buf][kt * 16 + ln][0];
            kf[kt][0] = *(const short8*)(krow + ((quad ^ lnx) * 8));
            kf[kt][1] = *(const short8*)(krow + (((4 + quad) ^ lnx) * 8));
        }

        short8 pb[2][2];                     // P^T B-fragments [g][32-key chunk]
#pragma unroll
        for (int g = 0; g < 2; ++g) {
            int qg = qw + g * 16;
            // S^T: D[key=quad*4+r][qrow=ln], C-init = -m(qrow)
            float4v st[4];
#pragma unroll
            for (int kt = 0; kt < 4; ++kt) {
                float4v sa = {-mrow[g], -mrow[g], -mrow[g], -mrow[g]};
                sa = __builtin_amdgcn_mfma_f32_16x16x32_bf16(kf[kt][0], qf[g][0], sa, 0, 0, 0);
                sa = __builtin_amdgcn_mfma_f32_16x16x32_bf16(kf[kt][1], qf[g][1], sa, 0, 0, 0);
                st[kt] = sa;
            }
            if (k0 + 63 <= qg) {
                // fully unmasked (wave-uniform fast path)
#pragma unroll
                for (int c = 0; c < 2; ++c) {
                    uint4v pk;
#pragma unroll
                    for (int kt2 = 0; kt2 < 2; ++kt2) {
                        float e0 = exp2f(st[c * 2 + kt2][0]);
                        float e1 = exp2f(st[c * 2 + kt2][1]);
                        float e2 = exp2f(st[c * 2 + kt2][2]);
                        float e3 = exp2f(st[c * 2 + kt2][3]);
                        pk[kt2 * 2 + 0] = pack2bf(e0, e1);
                        pk[kt2 * 2 + 1] = pack2bf(e2, e3);
                    }
                    pb[g][c] = *(short8*)&pk;
                }
            } else {
                int qr = qg + ln;            // this lane's q-row
#pragma unroll
                for (int c = 0; c < 2; ++c) {
                    uint4v pk;
#pragma unroll
                    for (int kt2 = 0; kt2 < 2; ++kt2) {
                        int kt = c * 2 + kt2;
                        float e[4];
#pragma unroll
                        for (int r = 0; r < 4; ++r) {
                            int kg = k0 + kt * 16 + quad * 4 + r;
                            float arg = (kg <= qr) ? st[kt][r] : -1e30f;
                            e[r] = exp2f(arg);
                        }
                        pk[kt2 * 2 + 0] = pack2bf(e[0], e[1]);
                        pk[kt2 * 2 + 1] = pack2bf(e[2], e[3]);
                    }
                    pb[g][c] = *(short8*)&pk;
                }
            }
        }

        // O^T += V^T P^T ; l += ones P^T
#pragma unroll
        for (int dc = 0; dc < 4; ++dc) {
            const u16* vrow = &Vs[buf][dc * 16 + ln][0];
            short8 vf0 = *(const short8*)(vrow + ((quad ^ lnx) * 8));
            short8 vf1 = *(const short8*)(vrow + (((4 + quad) ^ lnx) * 8));
#pragma unroll
            for (int g = 0; g < 2; ++g) {
                accO[g][dc] = __builtin_amdgcn_mfma_f32_16x16x32_bf16(vf0, pb[g][0], accO[g][dc], 0, 0, 0);
                accO[g][dc] = __builtin_amdgcn_mfma_f32_16x16x32_bf16(vf1, pb[g][1], accO[g][dc], 0, 0, 0);
            }
        }
#pragma unroll
        for (int g = 0; g < 2; ++g) {
            accL[g] = __builtin_amdgcn_mfma_f32_16x16x32_bf16(ones, pb[g][0], accL[g], 0, 0, 0);
            accL[g] = __builtin_amdgcn_mfma_f32_16x16x32_bf16(ones, pb[g][1], accL[g], 0, 0, 0);
        }
    }

#pragma unroll
    for (int g = 0; g < 2; ++g) {
        float rinv = 1.0f / accL[g][0];      // l for qrow=ln (same in all rows)
        int qg = qw + g * 16;
        int qr = qg + ln;
        if (s == 2) {
            // O^T is already the transposed layout; apply perm32 on qrow for L2's Vt
            u16* Otb = Ot + (size_t)(b * H_ + h) * (64 * (size_t)N_);
            int pos = perm32(qr & (N_ - 1)) + (qr & ~(N_ - 1));
#pragma unroll
            for (int dc = 0; dc < 4; ++dc)
#pragma unroll
                for (int r = 0; r < 4; ++r)
                    Otb[(size_t)(dc * 16 + quad * 4 + r) * N_ + pos] =
                        f2bf(accO[g][dc][r] * rinv);
        } else {
            u16* Ob = O + (size_t)s * o_set_stride + ((size_t)b * N_) * DI_ + h * 64;
#pragma unroll
            for (int dc = 0; dc < 4; ++dc) {
                uint2 pk;
                pk.x = pack2bf(accO[g][dc][0] * rinv, accO[g][dc][1] * rinv);
                pk.y = pack2bf(accO[g][dc][2] * rinv, accO[g][dc][3] * rinv);
                *(uint2*)(Ob + (size_t)qr * DI_ + dc * 16 + quad * 4) = pk;
            }
        }
    }
}

extern "C" void kernel_launch(void* const* d_in, const int* in_sizes, int n_in,
                              void* d_out, int out_size, void* d_ws, size_t ws_size,
                              hipStream_t stream) {
    const float* tok     = (const float*)d_in[0];
    const float* w_norm  = (const float*)d_in[1];
    const float* w_q     = (const float*)d_in[2];
    const float* w_k     = (const float*)d_in[3];
    const float* w_v     = (const float*)d_in[4];
    const float* w_keyn  = (const float*)d_in[5];
    const float* w_nestk = (const float*)d_in[6];
    const float* w_o     = (const float*)d_in[7];

    char* ws = (char*)d_ws;
    const size_t MB = 1024 * 1024;
    u16* QKVB  = (u16*)(ws + 0 * MB);    // [0,56)   4096 x 7168 bf16
    u16* VtB   = (u16*)(ws + 56 * MB);   // [56,80)
    u16* NQKV  = (u16*)(ws + 80 * MB);   // [80,96)  sets 0,1 token-major (written by L1)
    u16* WQKVT = (u16*)(ws + 80 * MB);   // [80,94)  dead before L1 writes NQKV
    u16* NVt   = (u16*)(ws + 96 * MB);   // [96,104) set 2 transposed (written by L1)
    u16* XN    = (u16*)(ws + 96 * MB);   // [96,104) dead after QKV GEMM
    u16* OUT2  = (u16*)(ws + 104 * MB);  // [104,112) written by L2
    u16* WOT   = (u16*)(ws + 80 * MB);   // [80,82)  re-created after L2 (NQKV dead)

    const size_t SET = (size_t)B_ * N_ * DI_;

    k_transpose_qkv<<<dim3(224, 32), dim3(32, 8), 0, stream>>>(w_q, w_k, w_v, WQKVT);

    k_rmsnorm_x<<<B_ * N_, 256, 0, stream>>>(tok, w_norm, XN);

    k_gemm_bt<false><<<dim3(32, 56), 256, 0, stream>>>(XN, WQKVT, QKVB, 1024, 7168);

    k_transpose_v<<<dim3(N_ / 64, 3 * B_ * H_), 256, 0, stream>>>(QKVB, VtB);

    k_rms_rope_k<<<(B_ * N_ * 3 * H_) / 4, 256, 0, stream>>>(QKVB, w_keyn, 7168, 1024, 3);

    k_flash<<<dim3(B_ * H_, N_ / 128, 3), 256, 0, stream>>>(
        QKVB, 7168, QKVB + 1024, VtB, NQKV, NVt, 7168, 1024, SET);

    k_rms_rope_k<<<(B_ * N_ * H_) / 4, 256, 0, stream>>>(NQKV + SET, w_nestk, 1024, 0, 1);

    k_flash<<<dim3(B_ * H_, N_ / 128, 1), 256, 0, stream>>>(
        NQKV, 1024, NQKV + SET, NVt, OUT2, NVt /*unused*/, 1024, 0, 0);

    k_transpose<<<dim3(32, 32), dim3(32, 8), 0, stream>>>(w_o, WOT, 1024, 1024);
    k_gemm_bt<true><<<dim3(32, 8), 256, 0, stream>>>(OUT2, WOT, (float*)d_out, 1024, 1024);
}